// Round 1
// baseline (889.364 us; speedup 1.0000x reference)
//
// CrossAttentionBlock_56813827392085 — full fused transformer block, bf16 MFMA internals.
// Workspace layout (~184 MB required):
//   WBF bf16 weights 13.6MB | XW f32 x 33.5MB | XN/QB/KB/VB bf16 16.8MB each |
//   HB bf16 67MB (ffn hidden / attn-out) | SM f32 smalls (ctx+ksum, memset 0) | DINV f32 1MB
#include <hip/hip_runtime.h>
#include <hip/hip_bf16.h>
#include <math.h>
#include <stdint.h>

typedef unsigned short u16;
typedef __attribute__((ext_vector_type(8))) short bh8;   // 8 x bf16 (4 VGPRs) MFMA frag
typedef __attribute__((ext_vector_type(4))) float fx4;   // MFMA accumulator frag

#define DEV static __device__ __forceinline__

DEV float bf2f(u16 u){ union{unsigned u; float f;} v; v.u = ((unsigned)u)<<16; return v.f; }
DEV u16 f2bf(float f){ union{float f; unsigned u;} v; v.f = f;
  return (u16)((v.u + 0x7fffu + ((v.u>>16)&1u))>>16); }               // RNE

DEV void async16(const u16* g, u16* l){
  // global -> LDS direct, 16B/lane; LDS dest = wave-uniform base + lane*16
  __builtin_amdgcn_global_load_lds((__attribute__((address_space(1))) void*)(uintptr_t)g,
                                   (__attribute__((address_space(3))) void*)l, 16, 0, 0);
}

// ---------------- weight fp32 -> bf16 pack ----------------
struct WDesc { const float* src[12]; int off[12]; };
__global__ __launch_bounds__(256) void convw_kernel(WDesc d, u16* __restrict__ dst){
  int i = blockIdx.x*256 + threadIdx.x;
  int s = 0;
  #pragma unroll
  for(int j=1;j<12;j++) if(i >= d.off[j]) s = j;
  dst[i] = f2bf(d.src[s][i - d.off[s]]);
}

// ---------------- LayerNorm (C=512), fp32 in -> bf16 out ----------------
DEV float wsum64(float s){
  s += __shfl_xor(s,1,64);  s += __shfl_xor(s,2,64);  s += __shfl_xor(s,4,64);
  s += __shfl_xor(s,8,64);  s += __shfl_xor(s,16,64); s += __shfl_xor(s,32,64);
  return s;
}
__global__ __launch_bounds__(256) void ln_kernel(const float* __restrict__ x,
    const float* __restrict__ g, const float* __restrict__ bta, u16* __restrict__ out){
  int row  = blockIdx.x*4 + (threadIdx.x>>6);
  int lane = threadIdx.x & 63;
  const float4* xr = (const float4*)(x + (size_t)row*512) + lane*2;
  float4 a = xr[0], c = xr[1];
  float s = a.x+a.y+a.z+a.w + c.x+c.y+c.z+c.w;
  float mean = wsum64(s) * (1.f/512.f);
  float d0=a.x-mean,d1=a.y-mean,d2=a.z-mean,d3=a.w-mean;
  float d4=c.x-mean,d5=c.y-mean,d6=c.z-mean,d7=c.w-mean;
  float sv = d0*d0+d1*d1+d2*d2+d3*d3+d4*d4+d5*d5+d6*d6+d7*d7;
  float rstd = rsqrtf(wsum64(sv)*(1.f/512.f) + 1e-5f);
  const float4* gr = (const float4*)g   + lane*2;
  const float4* br = (const float4*)bta + lane*2;
  float4 g0=gr[0], g1=gr[1], b0=br[0], b1=br[1];
  bh8 o;
  o[0]=(short)f2bf(d0*rstd*g0.x+b0.x); o[1]=(short)f2bf(d1*rstd*g0.y+b0.y);
  o[2]=(short)f2bf(d2*rstd*g0.z+b0.z); o[3]=(short)f2bf(d3*rstd*g0.w+b0.w);
  o[4]=(short)f2bf(d4*rstd*g1.x+b1.x); o[5]=(short)f2bf(d5*rstd*g1.y+b1.y);
  o[6]=(short)f2bf(d6*rstd*g1.z+b1.z); o[7]=(short)f2bf(d7*rstd*g1.w+b1.w);
  *(bh8*)(out + (size_t)row*512 + lane*8) = o;
}

// ---------------- GEMM C = A[MxK] * W[NxK]^T + bias, fused epilogues ----------------
// EPI 0: +bias -> bf16 | 1: +bias, softmax over wave's 64 cols (one head) -> bf16
// EPI 2: +bias, gelu(tanh) -> bf16 | 3: +bias + res -> fp32
template<int EPI>
__global__ __launch_bounds__(256) void gemm_bt(const u16* __restrict__ A,
    const u16* __restrict__ W, const float* __restrict__ bias,
    const float* __restrict__ res, void* __restrict__ out, int M, int N, int K){
  __shared__ __align__(16) u16 lsA[128*32];
  __shared__ __align__(16) u16 lsB[128*32];
  const int tid = threadIdx.x, lane = tid&63, w = tid>>6;
  const int quad = lane>>4, l15 = lane&15;
  const int bm = blockIdx.y, bn = blockIdx.x;
  const int wm = w&1, wn = w>>1;
  fx4 acc[4][4];
  #pragma unroll
  for(int i=0;i<4;i++)
    #pragma unroll
    for(int j=0;j<4;j++) acc[i][j] = (fx4){0.f,0.f,0.f,0.f};
  const u16* Ab = A + (size_t)bm*128*K;
  const u16* Wb = W + (size_t)bn*128*K;
  const int srow = w*32 + (lane>>2);     // staging: 16 rows x 4 lanes x 16B per wave-load
  const int scol = (lane&3)*8;
  for(int k0=0;k0<K;k0+=32){
    __syncthreads();
    async16(Ab + (size_t)srow*K      + k0 + scol, &lsA[(w*32   )*32]);
    async16(Ab + (size_t)(srow+16)*K + k0 + scol, &lsA[(w*32+16)*32]);
    async16(Wb + (size_t)srow*K      + k0 + scol, &lsB[(w*32   )*32]);
    async16(Wb + (size_t)(srow+16)*K + k0 + scol, &lsB[(w*32+16)*32]);
    __syncthreads();                    // drains vmcnt for global_load_lds
    bh8 af[4], bfx[4];
    #pragma unroll
    for(int t=0;t<4;t++){
      af[t]  = *(const bh8*)&lsA[(wm*64+t*16+l15)*32 + quad*8];
      bfx[t] = *(const bh8*)&lsB[(wn*64+t*16+l15)*32 + quad*8];
    }
    #pragma unroll
    for(int mt=0;mt<4;mt++)
      #pragma unroll
      for(int nt=0;nt<4;nt++)
        acc[mt][nt] = __builtin_amdgcn_mfma_f32_16x16x32_bf16(af[mt], bfx[nt], acc[mt][nt], 0,0,0);
  }
  const int colbase = bn*128 + wn*64;
  float bcol[4];
  #pragma unroll
  for(int nt=0;nt<4;nt++) bcol[nt] = bias[colbase + nt*16 + l15];

  if(EPI==3){
    float* of = (float*)out;
    #pragma unroll
    for(int mt=0;mt<4;mt++)
      #pragma unroll
      for(int r=0;r<4;r++){
        int row = bm*128 + wm*64 + mt*16 + quad*4 + r;
        size_t rb = (size_t)row*N;
        #pragma unroll
        for(int nt=0;nt<4;nt++){
          int col = colbase + nt*16 + l15;
          of[rb+col] = res[rb+col] + acc[mt][nt][r] + bcol[nt];
        }
      }
  } else if(EPI==1){
    u16* ob = (u16*)out;
    #pragma unroll
    for(int mt=0;mt<4;mt++)
      #pragma unroll
      for(int r=0;r<4;r++){
        float v0=acc[mt][0][r]+bcol[0], v1=acc[mt][1][r]+bcol[1];
        float v2=acc[mt][2][r]+bcol[2], v3=acc[mt][3][r]+bcol[3];
        float mx = fmaxf(fmaxf(v0,v1),fmaxf(v2,v3));
        mx = fmaxf(mx,__shfl_xor(mx,1,64)); mx = fmaxf(mx,__shfl_xor(mx,2,64));
        mx = fmaxf(mx,__shfl_xor(mx,4,64)); mx = fmaxf(mx,__shfl_xor(mx,8,64));
        float e0=__expf(v0-mx), e1=__expf(v1-mx), e2=__expf(v2-mx), e3=__expf(v3-mx);
        float s = e0+e1+e2+e3;
        s += __shfl_xor(s,1,64); s += __shfl_xor(s,2,64);
        s += __shfl_xor(s,4,64); s += __shfl_xor(s,8,64);
        float inv = 1.f/s;
        int row = bm*128 + wm*64 + mt*16 + quad*4 + r;
        size_t rb = (size_t)row*N;
        ob[rb+colbase+ 0+l15]=f2bf(e0*inv); ob[rb+colbase+16+l15]=f2bf(e1*inv);
        ob[rb+colbase+32+l15]=f2bf(e2*inv); ob[rb+colbase+48+l15]=f2bf(e3*inv);
      }
  } else {
    u16* ob = (u16*)out;
    #pragma unroll
    for(int mt=0;mt<4;mt++)
      #pragma unroll
      for(int r=0;r<4;r++){
        int row = bm*128 + wm*64 + mt*16 + quad*4 + r;
        size_t rb = (size_t)row*N;
        #pragma unroll
        for(int nt=0;nt<4;nt++){
          float vv = acc[mt][nt][r] + bcol[nt];
          if(EPI==2){
            float x3 = vv*vv*vv;
            vv = 0.5f*vv*(1.f + tanhf(0.7978845608f*(vv + 0.044715f*x3)));
          }
          ob[rb + colbase + nt*16 + l15] = f2bf(vv);
        }
      }
  }
}

// ---------------- column sums per batch: ksum[b][c] = sum_t k[b,t,c] ----------------
__global__ __launch_bounds__(256) void colsum_kernel(const u16* __restrict__ k,
                                                     float* __restrict__ ksum){
  int tid = threadIdx.x;
  int rbase = blockIdx.x*256;
  int b = rbase >> 12;
  float a0=0.f, a1=0.f;
  for(int r=0;r<256;r++){
    const u16* row = k + (size_t)(rbase+r)*512;
    a0 += bf2f(row[tid]); a1 += bf2f(row[tid+256]);
  }
  atomicAdd(&ksum[b*512+tid], a0);
  atomicAdd(&ksum[b*512+tid+256], a1);
}

// ---------------- ctx[b,h][d1][d2] = sum_t k[t][d1] v[t][d2] (MFMA, K=t) ----------------
__global__ __launch_bounds__(256) void ctx_kernel(const u16* __restrict__ kb,
    const u16* __restrict__ vb, float* __restrict__ ctx){
  __shared__ __align__(16) u16 lk[64*72];  // transposed [d][t], stride 72 (144B, 16B-mult)
  __shared__ __align__(16) u16 lv[64*72];
  const int tid=threadIdx.x, lane=tid&63, w=tid>>6, quad=lane>>4, l15=lane&15;
  const int bh = blockIdx.x, h = bh&7;
  const size_t rowbase = ((size_t)(bh>>3))*4096 + (size_t)blockIdx.y*512;
  const int mt0=(w&1)*32, nt0=(w>>1)*32;   // wave's 32x32 quadrant
  fx4 acc[2][2];
  #pragma unroll
  for(int i=0;i<2;i++)
    #pragma unroll
    for(int j=0;j<2;j++) acc[i][j] = (fx4){0.f,0.f,0.f,0.f};
  const int tl = tid>>2, part = tid&3;
  for(int it=0; it<8; it++){
    __syncthreads();
    {
      size_t gro = (rowbase + it*64 + tl)*512 + h*64 + part*16;
      bh8 k0 = *(const bh8*)(kb + gro); bh8 k1 = *(const bh8*)(kb + gro + 8);
      bh8 v0 = *(const bh8*)(vb + gro); bh8 v1 = *(const bh8*)(vb + gro + 8);
      #pragma unroll
      for(int j=0;j<8;j++){
        lk[(part*16+j  )*72 + tl] = (u16)k0[j];
        lk[(part*16+8+j)*72 + tl] = (u16)k1[j];
        lv[(part*16+j  )*72 + tl] = (u16)v0[j];
        lv[(part*16+8+j)*72 + tl] = (u16)v1[j];
      }
    }
    __syncthreads();
    #pragma unroll
    for(int ks=0;ks<2;ks++){
      bh8 a0 = *(const bh8*)&lk[(mt0    +l15)*72 + ks*32 + quad*8];
      bh8 a1 = *(const bh8*)&lk[(mt0+16 +l15)*72 + ks*32 + quad*8];
      bh8 b0 = *(const bh8*)&lv[(nt0    +l15)*72 + ks*32 + quad*8];
      bh8 b1 = *(const bh8*)&lv[(nt0+16 +l15)*72 + ks*32 + quad*8];
      acc[0][0] = __builtin_amdgcn_mfma_f32_16x16x32_bf16(a0,b0,acc[0][0],0,0,0);
      acc[0][1] = __builtin_amdgcn_mfma_f32_16x16x32_bf16(a0,b1,acc[0][1],0,0,0);
      acc[1][0] = __builtin_amdgcn_mfma_f32_16x16x32_bf16(a1,b0,acc[1][0],0,0,0);
      acc[1][1] = __builtin_amdgcn_mfma_f32_16x16x32_bf16(a1,b1,acc[1][1],0,0,0);
    }
  }
  float* cb = ctx + (size_t)bh*4096;
  #pragma unroll
  for(int mi=0;mi<2;mi++)
    #pragma unroll
    for(int ni=0;ni<2;ni++)
      #pragma unroll
      for(int r=0;r<4;r++){
        int d1 = mt0 + mi*16 + quad*4 + r;
        int d2 = nt0 + ni*16 + l15;
        atomicAdd(&cb[d1*64 + d2], acc[mi][ni][r]);
      }
}

// ---------------- Dinv[i][token][h] = 1/(sum_d q*ksum + eps) ----------------
__global__ __launch_bounds__(256) void dinv_kernel(const u16* __restrict__ q,
    const float* __restrict__ ksum, float* __restrict__ dinv, int n_in, float eps){
  int gidx = blockIdx.x*256 + threadIdx.x;        // M*8 threads
  int token = gidx>>3, h = gidx&7, b = token>>12;
  const u16* qr = q + (size_t)token*512 + h*64;
  float qv[64];
  #pragma unroll
  for(int d=0;d<64;d++) qv[d] = bf2f(qr[d]);
  for(int i=0;i<n_in;i++){
    const float* ks = ksum + i*2048 + b*512 + h*64;
    float s = 0.f;
    #pragma unroll
    for(int d=0;d<64;d++) s += qv[d]*ks[d];
    dinv[(size_t)i*131072 + gidx] = 1.f/(s + eps);
  }
}

// ---------------- out = q + sum_i (q @ ctx_i) * Dinv_i  (identity-slab MFMA) ----------------
template<int NIN>
__global__ __launch_bounds__(256) void apply_kernel(const u16* __restrict__ q,
    const float* __restrict__ ctx, const float* __restrict__ dinv, u16* __restrict__ out){
  __shared__ __align__(16) u16 lctx[(NIN+1)*64*72];   // transposed [d2][d1], +identity slab
  const int tid=threadIdx.x, lane=tid&63, w=tid>>6, quad=lane>>4, l15=lane&15;
  const int bh = blockIdx.x, b=bh>>3, h=bh&7;
  {
    int base = tid*16;
    int d1 = base>>6, d2b = base&63;
    #pragma unroll
    for(int s=0;s<=NIN;s++){
      u16* dst = &lctx[s*64*72];
      if(s<NIN){
        const float* sp = ctx + ((size_t)s*32 + bh)*4096 + base;
        #pragma unroll
        for(int j=0;j<16;j++) dst[(d2b+j)*72 + d1] = f2bf(sp[j]);
      } else {
        #pragma unroll
        for(int j=0;j<16;j++) dst[(d2b+j)*72 + d1] = ((d2b+j)==d1) ? (u16)0x3f80 : (u16)0;
      }
    }
  }
  __syncthreads();
  bh8 bfr[NIN+1][4][2];
  #pragma unroll
  for(int s=0;s<=NIN;s++)
    #pragma unroll
    for(int nt=0;nt<4;nt++)
      #pragma unroll
      for(int ks=0;ks<2;ks++)
        bfr[s][nt][ks] = *(const bh8*)&lctx[s*64*72 + (nt*16+l15)*72 + ks*32 + quad*8];
  const size_t tb0 = (size_t)b*4096 + (size_t)blockIdx.y*256 + w*64;
  for(int g=0;g<4;g++){
    size_t tb = tb0 + g*16;
    const u16* qr = q + (tb + l15)*512 + h*64;
    bh8 a0 = *(const bh8*)(qr + quad*8);
    bh8 a1 = *(const bh8*)(qr + 32 + quad*8);
    fx4 outv[4];
    #pragma unroll
    for(int nt=0;nt<4;nt++) outv[nt] = (fx4){0.f,0.f,0.f,0.f};
    #pragma unroll
    for(int s=0;s<=NIN;s++){
      fx4 c[4];
      #pragma unroll
      for(int nt=0;nt<4;nt++){
        c[nt] = (fx4){0.f,0.f,0.f,0.f};
        c[nt] = __builtin_amdgcn_mfma_f32_16x16x32_bf16(a0, bfr[s][nt][0], c[nt], 0,0,0);
        c[nt] = __builtin_amdgcn_mfma_f32_16x16x32_bf16(a1, bfr[s][nt][1], c[nt], 0,0,0);
      }
      float dv[4];
      #pragma unroll
      for(int r=0;r<4;r++)
        dv[r] = (s==NIN) ? 1.f : dinv[(size_t)s*131072 + (tb+quad*4+r)*8 + h];
      #pragma unroll
      for(int nt=0;nt<4;nt++)
        #pragma unroll
        for(int r=0;r<4;r++) outv[nt][r] += c[nt][r]*dv[r];
    }
    #pragma unroll
    for(int nt=0;nt<4;nt++)
      #pragma unroll
      for(int r=0;r<4;r++)
        out[(tb+quad*4+r)*512 + h*64 + nt*16 + l15] = f2bf(outv[nt][r]);
  }
}

// =========================================================================
extern "C" void kernel_launch(void* const* d_in, const int* in_sizes, int n_in,
                              void* d_out, int out_size, void* d_ws, size_t ws_size,
                              hipStream_t stream){
  const float* x_in =(const float*)d_in[0];
  const float* ys   =(const float*)d_in[1];
  const float* ln1g =(const float*)d_in[2],  *ln1b=(const float*)d_in[3];
  const float* ln2g =(const float*)d_in[4],  *ln2b=(const float*)d_in[5];
  const float* ln3g =(const float*)d_in[6],  *ln3b=(const float*)d_in[7];
  const float* ln4g =(const float*)d_in[8],  *ln4b=(const float*)d_in[9];
  const float* ln5g =(const float*)d_in[10], *ln5b=(const float*)d_in[11];
  const float* ca_wq=(const float*)d_in[12], *ca_bq=(const float*)d_in[13];
  const float* ca_wk=(const float*)d_in[14], *ca_bk=(const float*)d_in[15];
  const float* ca_wv=(const float*)d_in[16], *ca_bv=(const float*)d_in[17];
  const float* ca_wo=(const float*)d_in[18], *ca_bo=(const float*)d_in[19];
  const float* sa_wq=(const float*)d_in[20], *sa_bq=(const float*)d_in[21];
  const float* sa_wk=(const float*)d_in[22], *sa_bk=(const float*)d_in[23];
  const float* sa_wv=(const float*)d_in[24], *sa_bv=(const float*)d_in[25];
  const float* sa_wo=(const float*)d_in[26], *sa_bo=(const float*)d_in[27];
  const float* f1w1 =(const float*)d_in[28], *f1b1=(const float*)d_in[29];
  const float* f1w2 =(const float*)d_in[30], *f1b2=(const float*)d_in[31];
  const float* f2w1 =(const float*)d_in[32], *f2b1=(const float*)d_in[33];
  const float* f2w2 =(const float*)d_in[34], *f2b2=(const float*)d_in[35];

  char* p = (char*)d_ws;
  u16*   WBF = (u16*)p;    p += 13631488;   // 6,815,744 bf16 weights
  float* XW  = (float*)p;  p += 33554432;   // residual stream fp32 [M,512]
  u16*   XN  = (u16*)p;    p += 16777216;   // LN output bf16
  u16*   QB  = (u16*)p;    p += 16777216;
  u16*   KB  = (u16*)p;    p += 16777216;
  u16*   VB  = (u16*)p;    p += 16777216;
  u16*   HB  = (u16*)p;    p += 67108864;   // ffn hidden [M,2048] bf16; also attn-out
  float* SM  = (float*)p;  p += 1597440;    // ctx + ksum (zeroed)
  float* DINV= (float*)p;  p += 1048576;
  float* CTXC = SM;                          // [2][32][4096]
  float* CTXS = SM + 262144;                 // [32][4096]
  float* KSC  = SM + 393216;                 // [2][4][512]
  float* KSS  = SM + 397312;                 // [4][512]
  u16*   OUTB = HB;

  WDesc wd;
  const float* wsrc[12] = {ca_wq,ca_wk,ca_wv,ca_wo,sa_wq,sa_wk,sa_wv,sa_wo,f1w1,f1w2,f2w1,f2w2};
  const int    woff[12] = {0,262144,786432,1310720,1572864,1835008,2097152,2359296,
                           2621440,3670016,4718592,5767168};
  for(int i=0;i<12;i++){ wd.src[i]=wsrc[i]; wd.off[i]=woff[i]; }
  convw_kernel<<<26624,256,0,stream>>>(wd, WBF);
  hipMemsetAsync(SM, 0, 399360*sizeof(float), stream);

  // ---- cross attention ----
  ln_kernel<<<4096,256,0,stream>>>(x_in, ln1g, ln1b, XN);
  gemm_bt<1><<<dim3(4,128),256,0,stream>>>(XN, WBF+0, ca_bq, nullptr, QB, 16384,512,512);
  for(int i=0;i<2;i++){
    ln_kernel<<<4096,256,0,stream>>>(ys + (size_t)i*16384*512, ln2g+i*512, ln2b+i*512, XN);
    gemm_bt<1><<<dim3(4,128),256,0,stream>>>(XN, WBF+262144+i*262144, ca_bk+i*512, nullptr, KB, 16384,512,512);
    gemm_bt<0><<<dim3(4,128),256,0,stream>>>(XN, WBF+786432+i*262144, ca_bv+i*512, nullptr, VB, 16384,512,512);
    colsum_kernel<<<64,256,0,stream>>>(KB, KSC + i*2048);
    ctx_kernel<<<dim3(32,8),256,0,stream>>>(KB, VB, CTXC + (size_t)i*131072);
  }
  dinv_kernel<<<512,256,0,stream>>>(QB, KSC, DINV, 2, 1e-8f);
  apply_kernel<2><<<dim3(32,16),256,0,stream>>>(QB, CTXC, DINV, OUTB);
  gemm_bt<3><<<dim3(4,128),256,0,stream>>>(OUTB, WBF+1310720, ca_bo, x_in, XW, 16384,512,512);

  // ---- FFN 1 ----
  ln_kernel<<<4096,256,0,stream>>>(XW, ln3g, ln3b, XN);
  gemm_bt<2><<<dim3(16,128),256,0,stream>>>(XN, WBF+2621440, f1b1, nullptr, HB, 16384,2048,512);
  gemm_bt<3><<<dim3(4,128),256,0,stream>>>(HB, WBF+3670016, f1b2, XW, XW, 16384,512,2048);

  // ---- linear self attention ----
  ln_kernel<<<4096,256,0,stream>>>(XW, ln4g, ln4b, XN);
  gemm_bt<1><<<dim3(4,128),256,0,stream>>>(XN, WBF+1572864, sa_bq, nullptr, QB, 16384,512,512);
  gemm_bt<1><<<dim3(4,128),256,0,stream>>>(XN, WBF+1835008, sa_bk, nullptr, KB, 16384,512,512);
  gemm_bt<0><<<dim3(4,128),256,0,stream>>>(XN, WBF+2097152, sa_bv, nullptr, VB, 16384,512,512);
  colsum_kernel<<<64,256,0,stream>>>(KB, KSS);
  ctx_kernel<<<dim3(32,8),256,0,stream>>>(KB, VB, CTXS);
  dinv_kernel<<<512,256,0,stream>>>(QB, KSS, DINV, 1, 0.f);
  apply_kernel<1><<<dim3(32,16),256,0,stream>>>(QB, CTXS, DINV, OUTB);
  gemm_bt<3><<<dim3(4,128),256,0,stream>>>(OUTB, WBF+2359296, sa_bo, XW, XW, 16384,512,512);

  // ---- FFN 2 ----
  ln_kernel<<<4096,256,0,stream>>>(XW, ln5g, ln5b, XN);
  gemm_bt<2><<<dim3(16,128),256,0,stream>>>(XN, WBF+4718592, f2b1, nullptr, HB, 16384,2048,512);
  gemm_bt<3><<<dim3(4,128),256,0,stream>>>(HB, WBF+5767168, f2b2, XW, (float*)d_out, 16384,512,2048);
}

// Round 2
// 803.828 us; speedup vs baseline: 1.1064x; 1.1064x over previous
//
// CrossAttentionBlock_56813827392085 — fused transformer block, bf16 MFMA internals. R2:
//  - fast exp-based gelu epilogue (was tanhf: VALU-bound, MfmaUtil 16%)
//  - colsum fused into softmax-GEMM epilogue (atomics), colsum kernels removed
//  - q/k/v merged into multi-output GEMM (gemm_qkv), 14->10 GEMM dispatches
//  - XCD-aware block swizzle in all GEMMs for L2 locality
#include <hip/hip_runtime.h>
#include <hip/hip_bf16.h>
#include <math.h>
#include <stdint.h>

typedef unsigned short u16;
typedef __attribute__((ext_vector_type(8))) short bh8;   // 8 x bf16 (4 VGPRs) MFMA frag
typedef __attribute__((ext_vector_type(4))) float fx4;   // MFMA accumulator frag

#define DEV static __device__ __forceinline__

DEV float bf2f(u16 u){ union{unsigned u; float f;} v; v.u = ((unsigned)u)<<16; return v.f; }
DEV u16 f2bf(float f){ union{float f; unsigned u;} v; v.f = f;
  return (u16)((v.u + 0x7fffu + ((v.u>>16)&1u))>>16); }               // RNE

DEV void async16(const u16* g, u16* l){
  __builtin_amdgcn_global_load_lds((__attribute__((address_space(1))) void*)(uintptr_t)g,
                                   (__attribute__((address_space(3))) void*)l, 16, 0, 0);
}

DEV float gelu_fast(float x){
  // 0.5x(1+tanh(0.79788456(x+0.044715x^3))), tanh via exp: ~13 VALU ops, branch-free
  float u = 0.7978845608f*(x + 0.044715f*x*x*x);
  float e = __expf(-2.f*fabsf(u));
  float t = __fdividef(1.f - e, 1.f + e);
  t = copysignf(t, u);
  return 0.5f*x*(1.f + t);
}

// ---------------- weight fp32 -> bf16 pack ----------------
struct WDesc { const float* src[14]; int off[14]; };
__global__ __launch_bounds__(256) void convw_kernel(WDesc d, u16* __restrict__ dst){
  int i = blockIdx.x*256 + threadIdx.x;
  int s = 0;
  #pragma unroll
  for(int j=1;j<14;j++) if(i >= d.off[j]) s = j;
  dst[i] = f2bf(d.src[s][i - d.off[s]]);
}

// ---------------- LayerNorm (C=512), fp32 in -> bf16 out ----------------
DEV float wsum64(float s){
  s += __shfl_xor(s,1,64);  s += __shfl_xor(s,2,64);  s += __shfl_xor(s,4,64);
  s += __shfl_xor(s,8,64);  s += __shfl_xor(s,16,64); s += __shfl_xor(s,32,64);
  return s;
}
__global__ __launch_bounds__(256) void ln_kernel(const float* __restrict__ x,
    const float* __restrict__ g, const float* __restrict__ bta, u16* __restrict__ out){
  int row  = blockIdx.x*4 + (threadIdx.x>>6);
  int lane = threadIdx.x & 63;
  const float4* xr = (const float4*)(x + (size_t)row*512) + lane*2;
  float4 a = xr[0], c = xr[1];
  float s = a.x+a.y+a.z+a.w + c.x+c.y+c.z+c.w;
  float mean = wsum64(s) * (1.f/512.f);
  float d0=a.x-mean,d1=a.y-mean,d2=a.z-mean,d3=a.w-mean;
  float d4=c.x-mean,d5=c.y-mean,d6=c.z-mean,d7=c.w-mean;
  float sv = d0*d0+d1*d1+d2*d2+d3*d3+d4*d4+d5*d5+d6*d6+d7*d7;
  float rstd = rsqrtf(wsum64(sv)*(1.f/512.f) + 1e-5f);
  const float4* gr = (const float4*)g   + lane*2;
  const float4* br = (const float4*)bta + lane*2;
  float4 g0=gr[0], g1=gr[1], b0=br[0], b1=br[1];
  bh8 o;
  o[0]=(short)f2bf(d0*rstd*g0.x+b0.x); o[1]=(short)f2bf(d1*rstd*g0.y+b0.y);
  o[2]=(short)f2bf(d2*rstd*g0.z+b0.z); o[3]=(short)f2bf(d3*rstd*g0.w+b0.w);
  o[4]=(short)f2bf(d4*rstd*g1.x+b1.x); o[5]=(short)f2bf(d5*rstd*g1.y+b1.y);
  o[6]=(short)f2bf(d6*rstd*g1.z+b1.z); o[7]=(short)f2bf(d7*rstd*g1.w+b1.w);
  *(bh8*)(out + (size_t)row*512 + lane*8) = o;
}

// XCD-aware swizzle: each XCD (round-robin by dispatch id) gets a contiguous bm band.
DEV void xcd_map(int nbx, int& bn, int& bm){
  int lid = blockIdx.y*nbx + blockIdx.x;
  int per = (nbx*128)>>3;
  int sid = (lid&7)*per + (lid>>3);
  bn = sid % nbx; bm = sid / nbx;
}

// ---------------- multi-output projection GEMM: C_sub = A * W_sub^T + bias ----------------
// Each 128-col sub-slice (bn>>2) routes to its own {out, bias, mode, ksum}.
// mode 0: plain bf16; mode 1: per-head softmax (wave's 64 cols = one head) bf16.
struct SubD { const float* bias; u16* out; float* ksum; int mode; };
struct Subs3 { SubD s[3]; };
__global__ __launch_bounds__(256) void gemm_qkv(const u16* __restrict__ A,
    const u16* __restrict__ W, Subs3 subs, int K){
  __shared__ __align__(16) u16 lsA[128*32];
  __shared__ __align__(16) u16 lsB[128*32];
  const int tid = threadIdx.x, lane = tid&63, w = tid>>6;
  const int quad = lane>>4, l15 = lane&15;
  int bn, bm; xcd_map(gridDim.x, bn, bm);
  const int wm = w&1, wn = w>>1;
  fx4 acc[4][4];
  #pragma unroll
  for(int i=0;i<4;i++)
    #pragma unroll
    for(int j=0;j<4;j++) acc[i][j] = (fx4){0.f,0.f,0.f,0.f};
  const u16* Ab = A + (size_t)bm*128*K;
  const u16* Wb = W + (size_t)bn*128*K;
  const int srow = w*32 + (lane>>2);
  const int scol = (lane&3)*8;
  for(int k0=0;k0<K;k0+=32){
    __syncthreads();
    async16(Ab + (size_t)srow*K      + k0 + scol, &lsA[(w*32   )*32]);
    async16(Ab + (size_t)(srow+16)*K + k0 + scol, &lsA[(w*32+16)*32]);
    async16(Wb + (size_t)srow*K      + k0 + scol, &lsB[(w*32   )*32]);
    async16(Wb + (size_t)(srow+16)*K + k0 + scol, &lsB[(w*32+16)*32]);
    __syncthreads();
    bh8 af[4], bfx[4];
    #pragma unroll
    for(int t=0;t<4;t++){
      af[t]  = *(const bh8*)&lsA[(wm*64+t*16+l15)*32 + quad*8];
      bfx[t] = *(const bh8*)&lsB[(wn*64+t*16+l15)*32 + quad*8];
    }
    #pragma unroll
    for(int mt=0;mt<4;mt++)
      #pragma unroll
      for(int nt=0;nt<4;nt++)
        acc[mt][nt] = __builtin_amdgcn_mfma_f32_16x16x32_bf16(af[mt], bfx[nt], acc[mt][nt], 0,0,0);
  }
  const SubD sub = subs.s[bn>>2];
  const int colw = (bn&3)*128 + wn*64;          // column within this sub's 512
  float bcol[4];
  #pragma unroll
  for(int nt=0;nt<4;nt++) bcol[nt] = sub.bias[colw + nt*16 + l15];

  if(sub.mode==1){
    float ksacc[4] = {0.f,0.f,0.f,0.f};
    #pragma unroll
    for(int mt=0;mt<4;mt++)
      #pragma unroll
      for(int r=0;r<4;r++){
        float v0=acc[mt][0][r]+bcol[0], v1=acc[mt][1][r]+bcol[1];
        float v2=acc[mt][2][r]+bcol[2], v3=acc[mt][3][r]+bcol[3];
        float mx = fmaxf(fmaxf(v0,v1),fmaxf(v2,v3));
        mx = fmaxf(mx,__shfl_xor(mx,1,64)); mx = fmaxf(mx,__shfl_xor(mx,2,64));
        mx = fmaxf(mx,__shfl_xor(mx,4,64)); mx = fmaxf(mx,__shfl_xor(mx,8,64));
        float e0=__expf(v0-mx), e1=__expf(v1-mx), e2=__expf(v2-mx), e3=__expf(v3-mx);
        float s = e0+e1+e2+e3;
        s += __shfl_xor(s,1,64); s += __shfl_xor(s,2,64);
        s += __shfl_xor(s,4,64); s += __shfl_xor(s,8,64);
        float inv = __fdividef(1.f, s);
        e0*=inv; e1*=inv; e2*=inv; e3*=inv;
        ksacc[0]+=e0; ksacc[1]+=e1; ksacc[2]+=e2; ksacc[3]+=e3;
        int row = bm*128 + wm*64 + mt*16 + quad*4 + r;
        size_t rb = (size_t)row*512;
        sub.out[rb+colw+ 0+l15]=f2bf(e0); sub.out[rb+colw+16+l15]=f2bf(e1);
        sub.out[rb+colw+32+l15]=f2bf(e2); sub.out[rb+colw+48+l15]=f2bf(e3);
      }
    if(sub.ksum){
      int b = bm>>5;                            // 4096 rows per batch, 32 bm-blocks
      #pragma unroll
      for(int nt=0;nt<4;nt++){
        float s = ksacc[nt];
        s += __shfl_xor(s,16,64); s += __shfl_xor(s,32,64);
        if(quad==0) atomicAdd(&sub.ksum[b*512 + colw + nt*16 + l15], s);
      }
    }
  } else {
    #pragma unroll
    for(int mt=0;mt<4;mt++)
      #pragma unroll
      for(int r=0;r<4;r++){
        int row = bm*128 + wm*64 + mt*16 + quad*4 + r;
        size_t rb = (size_t)row*512;
        #pragma unroll
        for(int nt=0;nt<4;nt++)
          sub.out[rb + colw + nt*16 + l15] = f2bf(acc[mt][nt][r] + bcol[nt]);
      }
  }
}

// ---------------- GEMM C = A[MxK] * W[NxK]^T + bias, EPI 2: gelu->bf16, 3: +res->fp32 ----
template<int EPI>
__global__ __launch_bounds__(256) void gemm_bt(const u16* __restrict__ A,
    const u16* __restrict__ W, const float* __restrict__ bias,
    const float* __restrict__ res, void* __restrict__ out, int N, int K){
  __shared__ __align__(16) u16 lsA[128*32];
  __shared__ __align__(16) u16 lsB[128*32];
  const int tid = threadIdx.x, lane = tid&63, w = tid>>6;
  const int quad = lane>>4, l15 = lane&15;
  int bn, bm; xcd_map(gridDim.x, bn, bm);
  const int wm = w&1, wn = w>>1;
  fx4 acc[4][4];
  #pragma unroll
  for(int i=0;i<4;i++)
    #pragma unroll
    for(int j=0;j<4;j++) acc[i][j] = (fx4){0.f,0.f,0.f,0.f};
  const u16* Ab = A + (size_t)bm*128*K;
  const u16* Wb = W + (size_t)bn*128*K;
  const int srow = w*32 + (lane>>2);
  const int scol = (lane&3)*8;
  for(int k0=0;k0<K;k0+=32){
    __syncthreads();
    async16(Ab + (size_t)srow*K      + k0 + scol, &lsA[(w*32   )*32]);
    async16(Ab + (size_t)(srow+16)*K + k0 + scol, &lsA[(w*32+16)*32]);
    async16(Wb + (size_t)srow*K      + k0 + scol, &lsB[(w*32   )*32]);
    async16(Wb + (size_t)(srow+16)*K + k0 + scol, &lsB[(w*32+16)*32]);
    __syncthreads();
    bh8 af[4], bfx[4];
    #pragma unroll
    for(int t=0;t<4;t++){
      af[t]  = *(const bh8*)&lsA[(wm*64+t*16+l15)*32 + quad*8];
      bfx[t] = *(const bh8*)&lsB[(wn*64+t*16+l15)*32 + quad*8];
    }
    #pragma unroll
    for(int mt=0;mt<4;mt++)
      #pragma unroll
      for(int nt=0;nt<4;nt++)
        acc[mt][nt] = __builtin_amdgcn_mfma_f32_16x16x32_bf16(af[mt], bfx[nt], acc[mt][nt], 0,0,0);
  }
  const int colbase = bn*128 + wn*64;
  float bcol[4];
  #pragma unroll
  for(int nt=0;nt<4;nt++) bcol[nt] = bias[colbase + nt*16 + l15];

  if(EPI==3){
    float* of = (float*)out;
    #pragma unroll
    for(int mt=0;mt<4;mt++)
      #pragma unroll
      for(int r=0;r<4;r++){
        int row = bm*128 + wm*64 + mt*16 + quad*4 + r;
        size_t rb = (size_t)row*N;
        #pragma unroll
        for(int nt=0;nt<4;nt++){
          int col = colbase + nt*16 + l15;
          of[rb+col] = res[rb+col] + acc[mt][nt][r] + bcol[nt];
        }
      }
  } else {
    u16* ob = (u16*)out;
    #pragma unroll
    for(int mt=0;mt<4;mt++)
      #pragma unroll
      for(int r=0;r<4;r++){
        int row = bm*128 + wm*64 + mt*16 + quad*4 + r;
        size_t rb = (size_t)row*N;
        #pragma unroll
        for(int nt=0;nt<4;nt++)
          ob[rb + colbase + nt*16 + l15] = f2bf(gelu_fast(acc[mt][nt][r] + bcol[nt]));
      }
  }
}

// ---------------- ctx[b,h][d1][d2] = sum_t k[t][d1] v[t][d2] (MFMA, K=t) ----------------
__global__ __launch_bounds__(256) void ctx_kernel(const u16* __restrict__ kb,
    const u16* __restrict__ vb, float* __restrict__ ctx){
  __shared__ __align__(16) u16 lk[64*72];  // transposed [d][t], stride 72
  __shared__ __align__(16) u16 lv[64*72];
  const int tid=threadIdx.x, lane=tid&63, w=tid>>6, quad=lane>>4, l15=lane&15;
  const int bh = blockIdx.x, h = bh&7;
  const size_t rowbase = ((size_t)(bh>>3))*4096 + (size_t)blockIdx.y*512;
  const int mt0=(w&1)*32, nt0=(w>>1)*32;
  fx4 acc[2][2];
  #pragma unroll
  for(int i=0;i<2;i++)
    #pragma unroll
    for(int j=0;j<2;j++) acc[i][j] = (fx4){0.f,0.f,0.f,0.f};
  const int tl = tid>>2, part = tid&3;
  for(int it=0; it<8; it++){
    __syncthreads();
    {
      size_t gro = (rowbase + it*64 + tl)*512 + h*64 + part*16;
      bh8 k0 = *(const bh8*)(kb + gro); bh8 k1 = *(const bh8*)(kb + gro + 8);
      bh8 v0 = *(const bh8*)(vb + gro); bh8 v1 = *(const bh8*)(vb + gro + 8);
      #pragma unroll
      for(int j=0;j<8;j++){
        lk[(part*16+j  )*72 + tl] = (u16)k0[j];
        lk[(part*16+8+j)*72 + tl] = (u16)k1[j];
        lv[(part*16+j  )*72 + tl] = (u16)v0[j];
        lv[(part*16+8+j)*72 + tl] = (u16)v1[j];
      }
    }
    __syncthreads();
    #pragma unroll
    for(int ks=0;ks<2;ks++){
      bh8 a0 = *(const bh8*)&lk[(mt0    +l15)*72 + ks*32 + quad*8];
      bh8 a1 = *(const bh8*)&lk[(mt0+16 +l15)*72 + ks*32 + quad*8];
      bh8 b0 = *(const bh8*)&lv[(nt0    +l15)*72 + ks*32 + quad*8];
      bh8 b1 = *(const bh8*)&lv[(nt0+16 +l15)*72 + ks*32 + quad*8];
      acc[0][0] = __builtin_amdgcn_mfma_f32_16x16x32_bf16(a0,b0,acc[0][0],0,0,0);
      acc[0][1] = __builtin_amdgcn_mfma_f32_16x16x32_bf16(a0,b1,acc[0][1],0,0,0);
      acc[1][0] = __builtin_amdgcn_mfma_f32_16x16x32_bf16(a1,b0,acc[1][0],0,0,0);
      acc[1][1] = __builtin_amdgcn_mfma_f32_16x16x32_bf16(a1,b1,acc[1][1],0,0,0);
    }
  }
  float* cb = ctx + (size_t)bh*4096;
  #pragma unroll
  for(int mi=0;mi<2;mi++)
    #pragma unroll
    for(int ni=0;ni<2;ni++)
      #pragma unroll
      for(int r=0;r<4;r++){
        int d1 = mt0 + mi*16 + quad*4 + r;
        int d2 = nt0 + ni*16 + l15;
        atomicAdd(&cb[d1*64 + d2], acc[mi][ni][r]);
      }
}

// ---------------- Dinv[i][token][h] = 1/(sum_d q*ksum + eps) ----------------
__global__ __launch_bounds__(256) void dinv_kernel(const u16* __restrict__ q,
    const float* __restrict__ ksum, float* __restrict__ dinv, int n_in, float eps){
  int gidx = blockIdx.x*256 + threadIdx.x;
  int token = gidx>>3, h = gidx&7, b = token>>12;
  const u16* qr = q + (size_t)token*512 + h*64;
  float qv[64];
  #pragma unroll
  for(int d=0;d<64;d++) qv[d] = bf2f(qr[d]);
  for(int i=0;i<n_in;i++){
    const float* ks = ksum + i*2048 + b*512 + h*64;
    float s = 0.f;
    #pragma unroll
    for(int d=0;d<64;d++) s += qv[d]*ks[d];
    dinv[(size_t)i*131072 + gidx] = __fdividef(1.f, s + eps);
  }
}

// ---------------- out = q + sum_i (q @ ctx_i) * Dinv_i  (identity-slab MFMA) ----------------
template<int NIN>
__global__ __launch_bounds__(256) void apply_kernel(const u16* __restrict__ q,
    const float* __restrict__ ctx, const float* __restrict__ dinv, u16* __restrict__ out){
  __shared__ __align__(16) u16 lctx[(NIN+1)*64*72];
  const int tid=threadIdx.x, lane=tid&63, w=tid>>6, quad=lane>>4, l15=lane&15;
  const int bh = blockIdx.x, b=bh>>3, h=bh&7;
  {
    int base = tid*16;
    int d1 = base>>6, d2b = base&63;
    #pragma unroll
    for(int s=0;s<=NIN;s++){
      u16* dst = &lctx[s*64*72];
      if(s<NIN){
        const float* sp = ctx + ((size_t)s*32 + bh)*4096 + base;
        #pragma unroll
        for(int j=0;j<16;j++) dst[(d2b+j)*72 + d1] = f2bf(sp[j]);
      } else {
        #pragma unroll
        for(int j=0;j<16;j++) dst[(d2b+j)*72 + d1] = ((d2b+j)==d1) ? (u16)0x3f80 : (u16)0;
      }
    }
  }
  __syncthreads();
  bh8 bfr[NIN+1][4][2];
  #pragma unroll
  for(int s=0;s<=NIN;s++)
    #pragma unroll
    for(int nt=0;nt<4;nt++)
      #pragma unroll
      for(int ks=0;ks<2;ks++)
        bfr[s][nt][ks] = *(const bh8*)&lctx[s*64*72 + (nt*16+l15)*72 + ks*32 + quad*8];
  const size_t tb0 = (size_t)b*4096 + (size_t)blockIdx.y*256 + w*64;
  for(int g=0;g<4;g++){
    size_t tb = tb0 + g*16;
    const u16* qr = q + (tb + l15)*512 + h*64;
    bh8 a0 = *(const bh8*)(qr + quad*8);
    bh8 a1 = *(const bh8*)(qr + 32 + quad*8);
    fx4 outv[4];
    #pragma unroll
    for(int nt=0;nt<4;nt++) outv[nt] = (fx4){0.f,0.f,0.f,0.f};
    #pragma unroll
    for(int s=0;s<=NIN;s++){
      fx4 c[4];
      #pragma unroll
      for(int nt=0;nt<4;nt++){
        c[nt] = (fx4){0.f,0.f,0.f,0.f};
        c[nt] = __builtin_amdgcn_mfma_f32_16x16x32_bf16(a0, bfr[s][nt][0], c[nt], 0,0,0);
        c[nt] = __builtin_amdgcn_mfma_f32_16x16x32_bf16(a1, bfr[s][nt][1], c[nt], 0,0,0);
      }
      float dv[4];
      #pragma unroll
      for(int r=0;r<4;r++)
        dv[r] = (s==NIN) ? 1.f : dinv[(size_t)s*131072 + (tb+quad*4+r)*8 + h];
      #pragma unroll
      for(int nt=0;nt<4;nt++)
        #pragma unroll
        for(int r=0;r<4;r++) outv[nt][r] += c[nt][r]*dv[r];
    }
    #pragma unroll
    for(int nt=0;nt<4;nt++)
      #pragma unroll
      for(int r=0;r<4;r++)
        out[(tb+quad*4+r)*512 + h*64 + nt*16 + l15] = f2bf(outv[nt][r]);
  }
}

// =========================================================================
extern "C" void kernel_launch(void* const* d_in, const int* in_sizes, int n_in,
                              void* d_out, int out_size, void* d_ws, size_t ws_size,
                              hipStream_t stream){
  const float* x_in =(const float*)d_in[0];
  const float* ys   =(const float*)d_in[1];
  const float* ln1g =(const float*)d_in[2],  *ln1b=(const float*)d_in[3];
  const float* ln2g =(const float*)d_in[4],  *ln2b=(const float*)d_in[5];
  const float* ln3g =(const float*)d_in[6],  *ln3b=(const float*)d_in[7];
  const float* ln4g =(const float*)d_in[8],  *ln4b=(const float*)d_in[9];
  const float* ln5g =(const float*)d_in[10], *ln5b=(const float*)d_in[11];
  const float* ca_wq=(const float*)d_in[12], *ca_bq=(const float*)d_in[13];
  const float* ca_wk=(const float*)d_in[14], *ca_bk=(const float*)d_in[15];
  const float* ca_wv=(const float*)d_in[16], *ca_bv=(const float*)d_in[17];
  const float* ca_wo=(const float*)d_in[18], *ca_bo=(const float*)d_in[19];
  const float* sa_wq=(const float*)d_in[20], *sa_bq=(const float*)d_in[21];
  const float* sa_wk=(const float*)d_in[22], *sa_bk=(const float*)d_in[23];
  const float* sa_wv=(const float*)d_in[24], *sa_bv=(const float*)d_in[25];
  const float* sa_wo=(const float*)d_in[26], *sa_bo=(const float*)d_in[27];
  const float* f1w1 =(const float*)d_in[28], *f1b1=(const float*)d_in[29];
  const float* f1w2 =(const float*)d_in[30], *f1b2=(const float*)d_in[31];
  const float* f2w1 =(const float*)d_in[32], *f2b1=(const float*)d_in[33];
  const float* f2w2 =(const float*)d_in[34], *f2b2=(const float*)d_in[35];

  char* p = (char*)d_ws;
  u16*   WBF = (u16*)p;    p += 13631488;
  float* XW  = (float*)p;  p += 33554432;
  u16*   XN  = (u16*)p;    p += 16777216;
  u16*   QB  = (u16*)p;    p += 16777216;
  u16*   KB  = (u16*)p;    p += 16777216;
  u16*   VB  = (u16*)p;    p += 16777216;
  u16*   HB  = (u16*)p;    p += 67108864;
  float* SM  = (float*)p;  p += 1597440;
  float* DINV= (float*)p;  p += 1048576;
  float* CTXC = SM;                          // [2][32][4096]
  float* CTXS = SM + 262144;                 // [32][4096]
  float* KSC  = SM + 393216;                 // [2][4][512]
  float* KSS  = SM + 397312;                 // [4][512]
  u16*   OUTB = HB;

  // weight pack order: ca_wq | kv0 | kv1 | ca_wo | sa_qkv | sa_wo | ffn
  WDesc wd;
  const float* wsrc[14] = {ca_wq, ca_wk, ca_wv, ca_wk+262144, ca_wv+262144, ca_wo,
                           sa_wq, sa_wk, sa_wv, sa_wo, f1w1, f1w2, f2w1, f2w2};
  const int    woff[14] = {0, 262144, 524288, 786432, 1048576, 1310720,
                           1572864, 1835008, 2097152, 2359296,
                           2621440, 3670016, 4718592, 5767168};
  for(int i=0;i<14;i++){ wd.src[i]=wsrc[i]; wd.off[i]=woff[i]; }
  convw_kernel<<<26624,256,0,stream>>>(wd, WBF);
  hipMemsetAsync(SM, 0, 399360*sizeof(float), stream);

  SubD zsub = {nullptr,nullptr,nullptr,0};

  // ---- cross attention ----
  ln_kernel<<<4096,256,0,stream>>>(x_in, ln1g, ln1b, XN);
  { Subs3 s = {{ {ca_bq, QB, nullptr, 1}, zsub, zsub }};
    gemm_qkv<<<dim3(4,128),256,0,stream>>>(XN, WBF+0, s, 512); }
  for(int i=0;i<2;i++){
    ln_kernel<<<4096,256,0,stream>>>(ys + (size_t)i*16384*512, ln2g+i*512, ln2b+i*512, XN);
    { Subs3 s = {{ {ca_bk+i*512, KB, KSC+i*2048, 1}, {ca_bv+i*512, VB, nullptr, 0}, zsub }};
      gemm_qkv<<<dim3(8,128),256,0,stream>>>(XN, WBF+262144+i*524288, s, 512); }
    ctx_kernel<<<dim3(32,8),256,0,stream>>>(KB, VB, CTXC + (size_t)i*131072);
  }
  dinv_kernel<<<512,256,0,stream>>>(QB, KSC, DINV, 2, 1e-8f);
  apply_kernel<2><<<dim3(32,16),256,0,stream>>>(QB, CTXC, DINV, OUTB);
  gemm_bt<3><<<dim3(4,128),256,0,stream>>>(OUTB, WBF+1310720, ca_bo, x_in, XW, 512, 512);

  // ---- FFN 1 ----
  ln_kernel<<<4096,256,0,stream>>>(XW, ln3g, ln3b, XN);
  gemm_bt<2><<<dim3(16,128),256,0,stream>>>(XN, WBF+2621440, f1b1, nullptr, HB, 2048, 512);
  gemm_bt<3><<<dim3(4,128),256,0,stream>>>(HB, WBF+3670016, f1b2, XW, XW, 512, 2048);

  // ---- linear self attention ----
  ln_kernel<<<4096,256,0,stream>>>(XW, ln4g, ln4b, XN);
  { Subs3 s = {{ {sa_bq, QB, nullptr, 1}, {sa_bk, KB, KSS, 1}, {sa_bv, VB, nullptr, 0} }};
    gemm_qkv<<<dim3(12,128),256,0,stream>>>(XN, WBF+1572864, s, 512); }
  ctx_kernel<<<dim3(32,8),256,0,stream>>>(KB, VB, CTXS);
  dinv_kernel<<<512,256,0,stream>>>(QB, KSS, DINV, 1, 0.f);
  apply_kernel<1><<<dim3(32,16),256,0,stream>>>(QB, CTXS, DINV, OUTB);
  gemm_bt<3><<<dim3(4,128),256,0,stream>>>(OUTB, WBF+2359296, sa_bo, XW, XW, 512, 512);

  // ---- FFN 2 ----
  ln_kernel<<<4096,256,0,stream>>>(XW, ln5g, ln5b, XN);
  gemm_bt<2><<<dim3(16,128),256,0,stream>>>(XN, WBF+4718592, f2b1, nullptr, HB, 2048, 512);
  gemm_bt<3><<<dim3(4,128),256,0,stream>>>(HB, WBF+5767168, f2b2, XW, (float*)d_out, 512, 2048);
}